// Round 1
// baseline (6760.658 us; speedup 1.0000x reference)
//
#include <hip/hip_runtime.h>
#include <math.h>

#define NB 16384
#define HID 512
#define NV 128
#define NT 10

__device__ __forceinline__ float sigm(float v) { return 1.0f / (1.0f + expf(-v)); }

// ---------------- h0 = tanh(feats @ W_in^T + b_in) ----------------
// grid (NB/128, 512/64), block 256
__global__ __launch_bounds__(256) void h0_kernel(
    const float* __restrict__ x,     // NB x 272 (feats at col 16)
    const float* __restrict__ W,     // 512 x 256
    const float* __restrict__ bias,  // 512
    float* __restrict__ h0)          // NB x 512
{
    __shared__ __align__(16) float As[32][128];
    __shared__ __align__(16) float Ws[32][64];
    const int t = threadIdx.x;
    const int tx = t & 15, ty = t >> 4;
    const int mBase = blockIdx.x * 128, nBase = blockIdx.y * 64;
    const int kq = (t & 7) * 4, r8 = t >> 3;

    float4 acc[8];
    #pragma unroll
    for (int mi = 0; mi < 8; ++mi) acc[mi] = make_float4(0.f, 0.f, 0.f, 0.f);

    const float* aPtr = x + (size_t)(mBase + r8) * 272 + 16 + kq;
    const float* wPtr = W + (size_t)(nBase + r8) * 256 + kq;

    for (int kb = 0; kb < 8; ++kb) {
        const int k0 = kb * 32;
        __syncthreads();
        #pragma unroll
        for (int i = 0; i < 4; ++i) {
            float4 v = *(const float4*)(aPtr + (size_t)(i * 32) * 272 + k0);
            const int row = r8 + i * 32;
            const float vv[4] = {v.x, v.y, v.z, v.w};
            #pragma unroll
            for (int j = 0; j < 4; ++j) As[kq + j][row ^ ((kq + j) & 28)] = vv[j];
        }
        #pragma unroll
        for (int i = 0; i < 2; ++i) {
            float4 v = *(const float4*)(wPtr + (size_t)(i * 32) * 256 + k0);
            const int row = r8 + i * 32;
            const float vv[4] = {v.x, v.y, v.z, v.w};
            #pragma unroll
            for (int j = 0; j < 4; ++j) Ws[kq + j][row ^ ((kq + j) & 28)] = vv[j];
        }
        __syncthreads();
        #pragma unroll 8
        for (int k = 0; k < 32; ++k) {
            const int s = k & 28;
            float4 a0 = *(const float4*)&As[k][(ty * 8) ^ s];
            float4 a1 = *(const float4*)&As[k][((ty * 8) + 4) ^ s];
            float4 bb = *(const float4*)&Ws[k][(tx * 4) ^ s];
            const float am[8] = {a0.x, a0.y, a0.z, a0.w, a1.x, a1.y, a1.z, a1.w};
            #pragma unroll
            for (int mi = 0; mi < 8; ++mi) {
                acc[mi].x += am[mi] * bb.x;
                acc[mi].y += am[mi] * bb.y;
                acc[mi].z += am[mi] * bb.z;
                acc[mi].w += am[mi] * bb.w;
            }
        }
    }
    const int j0 = nBase + tx * 4;
    const float4 b4 = *(const float4*)&bias[j0];
    #pragma unroll
    for (int mi = 0; mi < 8; ++mi) {
        const int row = mBase + ty * 8 + mi;
        float4 o;
        o.x = tanhf(acc[mi].x + b4.x);
        o.y = tanhf(acc[mi].y + b4.y);
        o.z = tanhf(acc[mi].z + b4.z);
        o.w = tanhf(acc[mi].w + b4.w);
        *(float4*)&h0[(size_t)row * 512 + j0] = o;
    }
}

// ---------------- fused GRU step ----------------
// gh = h_in @ Whh^T (3 gate tiles), gi = gather(Wih[:, word]) + bih, GRU update
// grid (NB/128, 512/64), block 256
__global__ __launch_bounds__(256) void gru_kernel(
    const float* __restrict__ h_in,   // NB x 512
    float* __restrict__ h_out,        // NB x 512
    const float* __restrict__ Whh,    // 1536 x 512
    const float* __restrict__ Wih,    // 1536 x 128
    const float* __restrict__ bih,    // 1536
    const float* __restrict__ bhh,    // 1536
    const int* __restrict__ words,    // NB ints (or nullptr => zero input)
    const int h_zero)                 // 1 => h_in treated as zeros (skip GEMM)
{
    __shared__ __align__(16) float As[32][128];
    __shared__ __align__(16) float Ws[3][32][64];
    const int t = threadIdx.x;
    const int tx = t & 15, ty = t >> 4;
    const int mBase = blockIdx.x * 128, nBase = blockIdx.y * 64;
    const int kq = (t & 7) * 4, r8 = t >> 3;

    float4 acc[3][8];
    #pragma unroll
    for (int g = 0; g < 3; ++g)
        #pragma unroll
        for (int mi = 0; mi < 8; ++mi) acc[g][mi] = make_float4(0.f, 0.f, 0.f, 0.f);

    if (!h_zero) {
        const float* aPtr = h_in + (size_t)(mBase + r8) * 512 + kq;
        const float* w0 = Whh + (size_t)(nBase + r8) * 512 + kq;
        const float* w1 = Whh + (size_t)(512 + nBase + r8) * 512 + kq;
        const float* w2 = Whh + (size_t)(1024 + nBase + r8) * 512 + kq;

        for (int kb = 0; kb < 16; ++kb) {
            const int k0 = kb * 32;
            __syncthreads();
            #pragma unroll
            for (int i = 0; i < 4; ++i) {
                float4 v = *(const float4*)(aPtr + (size_t)(i * 32) * 512 + k0);
                const int row = r8 + i * 32;
                const float vv[4] = {v.x, v.y, v.z, v.w};
                #pragma unroll
                for (int j = 0; j < 4; ++j) As[kq + j][row ^ ((kq + j) & 28)] = vv[j];
            }
            #pragma unroll
            for (int i = 0; i < 2; ++i) {
                const int row = r8 + i * 32;
                float4 v0 = *(const float4*)(w0 + (size_t)(i * 32) * 512 + k0);
                float4 v1 = *(const float4*)(w1 + (size_t)(i * 32) * 512 + k0);
                float4 v2 = *(const float4*)(w2 + (size_t)(i * 32) * 512 + k0);
                const float a0[4] = {v0.x, v0.y, v0.z, v0.w};
                const float a1[4] = {v1.x, v1.y, v1.z, v1.w};
                const float a2[4] = {v2.x, v2.y, v2.z, v2.w};
                #pragma unroll
                for (int j = 0; j < 4; ++j) {
                    const int cc = row ^ ((kq + j) & 28);
                    Ws[0][kq + j][cc] = a0[j];
                    Ws[1][kq + j][cc] = a1[j];
                    Ws[2][kq + j][cc] = a2[j];
                }
            }
            __syncthreads();
            #pragma unroll 4
            for (int k = 0; k < 32; ++k) {
                const int s = k & 28;
                float4 a0 = *(const float4*)&As[k][(ty * 8) ^ s];
                float4 a1 = *(const float4*)&As[k][((ty * 8) + 4) ^ s];
                float4 b0 = *(const float4*)&Ws[0][k][(tx * 4) ^ s];
                float4 b1 = *(const float4*)&Ws[1][k][(tx * 4) ^ s];
                float4 b2 = *(const float4*)&Ws[2][k][(tx * 4) ^ s];
                const float am[8] = {a0.x, a0.y, a0.z, a0.w, a1.x, a1.y, a1.z, a1.w};
                #pragma unroll
                for (int mi = 0; mi < 8; ++mi) {
                    acc[0][mi].x += am[mi] * b0.x; acc[0][mi].y += am[mi] * b0.y;
                    acc[0][mi].z += am[mi] * b0.z; acc[0][mi].w += am[mi] * b0.w;
                    acc[1][mi].x += am[mi] * b1.x; acc[1][mi].y += am[mi] * b1.y;
                    acc[1][mi].z += am[mi] * b1.z; acc[1][mi].w += am[mi] * b1.w;
                    acc[2][mi].x += am[mi] * b2.x; acc[2][mi].y += am[mi] * b2.y;
                    acc[2][mi].z += am[mi] * b2.z; acc[2][mi].w += am[mi] * b2.w;
                }
            }
        }
    }

    const int j0 = nBase + tx * 4;
    const float4 br = *(const float4*)&bih[j0];
    const float4 bz = *(const float4*)&bih[512 + j0];
    const float4 bn = *(const float4*)&bih[1024 + j0];
    const float4 cr = *(const float4*)&bhh[j0];
    const float4 cz = *(const float4*)&bhh[512 + j0];
    const float4 cn = *(const float4*)&bhh[1024 + j0];

    #pragma unroll
    for (int mi = 0; mi < 8; ++mi) {
        const int row = mBase + ty * 8 + mi;
        const int idx = words ? words[row] : -1;
        float wr[4] = {0.f, 0.f, 0.f, 0.f};
        float wz[4] = {0.f, 0.f, 0.f, 0.f};
        float wn[4] = {0.f, 0.f, 0.f, 0.f};
        if (idx >= 0) {
            #pragma unroll
            for (int nj = 0; nj < 4; ++nj) {
                wr[nj] = Wih[(size_t)(j0 + nj) * 128 + idx];
                wz[nj] = Wih[(size_t)(512 + j0 + nj) * 128 + idx];
                wn[nj] = Wih[(size_t)(1024 + j0 + nj) * 128 + idx];
            }
        }
        float4 hold = make_float4(0.f, 0.f, 0.f, 0.f);
        if (!h_zero) hold = *(const float4*)&h_in[(size_t)row * 512 + j0];
        float4 o;
        {
            float r = sigm((wr[0] + br.x) + (acc[0][mi].x + cr.x));
            float z = sigm((wz[0] + bz.x) + (acc[1][mi].x + cz.x));
            float n = tanhf((wn[0] + bn.x) + r * (acc[2][mi].x + cn.x));
            o.x = (1.0f - z) * n + z * hold.x;
        }
        {
            float r = sigm((wr[1] + br.y) + (acc[0][mi].y + cr.y));
            float z = sigm((wz[1] + bz.y) + (acc[1][mi].y + cz.y));
            float n = tanhf((wn[1] + bn.y) + r * (acc[2][mi].y + cn.y));
            o.y = (1.0f - z) * n + z * hold.y;
        }
        {
            float r = sigm((wr[2] + br.z) + (acc[0][mi].z + cr.z));
            float z = sigm((wz[2] + bz.z) + (acc[1][mi].z + cz.z));
            float n = tanhf((wn[2] + bn.z) + r * (acc[2][mi].z + cn.z));
            o.z = (1.0f - z) * n + z * hold.z;
        }
        {
            float r = sigm((wr[3] + br.w) + (acc[0][mi].w + cr.w));
            float z = sigm((wz[3] + bz.w) + (acc[1][mi].w + cz.w));
            float n = tanhf((wn[3] + bn.w) + r * (acc[2][mi].w + cn.w));
            o.w = (1.0f - z) * n + z * hold.w;
        }
        *(float4*)&h_out[(size_t)row * 512 + j0] = o;
    }
}

// ---------------- logits = h @ W_sp^T + b_sp + gumbel; word = argmax ----------------
// grid (NB/64), block 256 (tx 0..31 -> 4 cols each; ty 0..7 -> 8 rows each)
__global__ __launch_bounds__(256) void argmax_kernel(
    const float* __restrict__ h,     // NB x 512
    const float* __restrict__ Wsp,   // 128 x 512
    const float* __restrict__ bsp,   // 128
    const float* __restrict__ gum,   // NB x 128 (this step's slice)
    int* __restrict__ wout)          // NB
{
    __shared__ __align__(16) float As[32][64];
    __shared__ __align__(16) float Ws[32][128];
    const int t = threadIdx.x;
    const int tx = t & 31, ty = t >> 5;
    const int mBase = blockIdx.x * 64;
    const int kq = (t & 7) * 4, r8 = t >> 3;

    float4 acc[8];
    #pragma unroll
    for (int mi = 0; mi < 8; ++mi) acc[mi] = make_float4(0.f, 0.f, 0.f, 0.f);

    const float* aPtr = h + (size_t)(mBase + r8) * 512 + kq;
    const float* wPtr = Wsp + (size_t)r8 * 512 + kq;

    for (int kb = 0; kb < 16; ++kb) {
        const int k0 = kb * 32;
        __syncthreads();
        #pragma unroll
        for (int i = 0; i < 2; ++i) {
            float4 v = *(const float4*)(aPtr + (size_t)(i * 32) * 512 + k0);
            const int row = r8 + i * 32;
            const float vv[4] = {v.x, v.y, v.z, v.w};
            #pragma unroll
            for (int j = 0; j < 4; ++j) As[kq + j][row ^ ((kq + j) & 28)] = vv[j];
        }
        #pragma unroll
        for (int i = 0; i < 4; ++i) {
            float4 v = *(const float4*)(wPtr + (size_t)(i * 32) * 512 + k0);
            const int row = r8 + i * 32;
            const float vv[4] = {v.x, v.y, v.z, v.w};
            #pragma unroll
            for (int j = 0; j < 4; ++j) Ws[kq + j][row ^ ((kq + j) & 28)] = vv[j];
        }
        __syncthreads();
        #pragma unroll 8
        for (int k = 0; k < 32; ++k) {
            const int s = k & 28;
            float4 a0 = *(const float4*)&As[k][(ty * 8) ^ s];
            float4 a1 = *(const float4*)&As[k][((ty * 8) + 4) ^ s];
            float4 bb = *(const float4*)&Ws[k][(tx * 4) ^ s];
            const float am[8] = {a0.x, a0.y, a0.z, a0.w, a1.x, a1.y, a1.z, a1.w};
            #pragma unroll
            for (int mi = 0; mi < 8; ++mi) {
                acc[mi].x += am[mi] * bb.x;
                acc[mi].y += am[mi] * bb.y;
                acc[mi].z += am[mi] * bb.z;
                acc[mi].w += am[mi] * bb.w;
            }
        }
    }

    const float4 b4 = *(const float4*)&bsp[tx * 4];
    #pragma unroll
    for (int mi = 0; mi < 8; ++mi) {
        const int row = mBase + ty * 8 + mi;
        const float4 g4 = *(const float4*)&gum[(size_t)row * 128 + tx * 4];
        float v[4];
        v[0] = acc[mi].x + b4.x + g4.x;
        v[1] = acc[mi].y + b4.y + g4.y;
        v[2] = acc[mi].z + b4.z + g4.z;
        v[3] = acc[mi].w + b4.w + g4.w;
        float bv = v[0];
        int bi = tx * 4;
        #pragma unroll
        for (int nj = 1; nj < 4; ++nj) {
            if (v[nj] > bv) { bv = v[nj]; bi = tx * 4 + nj; }
        }
        #pragma unroll
        for (int off = 1; off <= 16; off <<= 1) {
            float ov = __shfl_xor(bv, off, 64);
            int oi = __shfl_xor(bi, off, 64);
            if (ov > bv || (ov == bv && oi < bi)) { bv = ov; bi = oi; }
        }
        if (tx == 0) wout[row] = bi;
    }
}

// ---------------- alive mask -> effective word index (-1 = zero input) ----------------
__global__ __launch_bounds__(256) void eff_kernel(
    const int* __restrict__ words, int* __restrict__ eff)
{
    const int b = blockIdx.x * 256 + threadIdx.x;
    int alive = 1;
    #pragma unroll
    for (int t = 0; t < NT; ++t) {
        const int w = words[(size_t)t * NB + b];
        eff[(size_t)t * NB + b] = alive ? w : -1;
        alive = alive & (w != 0);
    }
}

// ---------------- score = [h_n, task] @ W_c^T + b_c ----------------
// grid (NB/256), block 256 (one row per thread)
__global__ __launch_bounds__(256) void score_kernel(
    const float* __restrict__ h,    // NB x 512
    const float* __restrict__ x,    // NB x 272 (task = cols 0..15)
    const float* __restrict__ Wc,   // 10 x 528
    const float* __restrict__ bc,   // 10
    float* __restrict__ out)        // NB x 10
{
    __shared__ __align__(16) float As[32][256];
    __shared__ __align__(16) float Wcs[10][528];
    const int t = threadIdx.x;
    const int b0 = blockIdx.x * 256;
    for (int q = t; q < 1320; q += 256) {
        *(float4*)&(((float*)Wcs)[q * 4]) = *(const float4*)&Wc[q * 4];
    }
    float acc[10];
    #pragma unroll
    for (int d = 0; d < 10; ++d) acc[d] = 0.f;

    const int kq = (t & 7) * 4, r8 = t >> 3;
    const float* aPtr = h + (size_t)(b0 + r8) * 512 + kq;

    for (int kb = 0; kb < 16; ++kb) {
        const int k0 = kb * 32;
        __syncthreads();
        #pragma unroll
        for (int i = 0; i < 8; ++i) {
            float4 v = *(const float4*)(aPtr + (size_t)(i * 32) * 512 + k0);
            const int row = r8 + i * 32;
            const float vv[4] = {v.x, v.y, v.z, v.w};
            #pragma unroll
            for (int j = 0; j < 4; ++j) As[kq + j][row ^ ((kq + j) & 28)] = vv[j];
        }
        __syncthreads();
        #pragma unroll
        for (int k4 = 0; k4 < 8; ++k4) {
            float vv[4];
            #pragma unroll
            for (int j = 0; j < 4; ++j) {
                const int k = k4 * 4 + j;
                vv[j] = As[k][t ^ (k & 28)];
            }
            #pragma unroll
            for (int d = 0; d < 10; ++d) {
                const float4 w = *(const float4*)&Wcs[d][k0 + k4 * 4];
                acc[d] += vv[0] * w.x + vv[1] * w.y + vv[2] * w.z + vv[3] * w.w;
            }
        }
    }
    const int row = b0 + t;
    #pragma unroll
    for (int j4 = 0; j4 < 4; ++j4) {
        const float4 tk = *(const float4*)&x[(size_t)row * 272 + j4 * 4];
        #pragma unroll
        for (int d = 0; d < 10; ++d) {
            const float4 w = *(const float4*)&Wcs[d][512 + j4 * 4];
            acc[d] += tk.x * w.x + tk.y * w.y + tk.z * w.z + tk.w * w.w;
        }
    }
    #pragma unroll
    for (int d = 0; d < 10; ++d) out[(size_t)row * 10 + d] = acc[d] + bc[d];
}

extern "C" void kernel_launch(void* const* d_in, const int* in_sizes, int n_in,
                              void* d_out, int out_size, void* d_ws, size_t ws_size,
                              hipStream_t stream) {
    const float* x      = (const float*)d_in[0];
    const float* gumbel = (const float*)d_in[1];
    const float* W_in   = (const float*)d_in[2];
    const float* b_in   = (const float*)d_in[3];
    const float* Wih_s  = (const float*)d_in[4];
    const float* Whh_s  = (const float*)d_in[5];
    const float* bih_s  = (const float*)d_in[6];
    const float* bhh_s  = (const float*)d_in[7];
    const float* W_sp   = (const float*)d_in[8];
    const float* b_sp   = (const float*)d_in[9];
    const float* Wih_r  = (const float*)d_in[10];
    const float* Whh_r  = (const float*)d_in[11];
    const float* bih_r  = (const float*)d_in[12];
    const float* bhh_r  = (const float*)d_in[13];
    const float* W_c    = (const float*)d_in[14];
    const float* b_c    = (const float*)d_in[15];
    float* out = (float*)d_out;

    float* hA = (float*)d_ws;
    float* hB = hA + (size_t)NB * 512;
    int* words = (int*)(hB + (size_t)NB * 512);
    int* eff = words + (size_t)NT * NB;

    const dim3 blk(256);
    const dim3 gGemm(NB / 128, 512 / 64);

    h0_kernel<<<gGemm, blk, 0, stream>>>(x, W_in, b_in, hA);

    for (int t = 0; t < NT; ++t) {
        const float* hin = (t % 2 == 0) ? hA : hB;
        float* hout = (t % 2 == 0) ? hB : hA;
        gru_kernel<<<gGemm, blk, 0, stream>>>(
            hin, hout, Whh_s, Wih_s, bih_s, bhh_s,
            (t == 0) ? (const int*)nullptr : (words + (size_t)(t - 1) * NB), 0);
        argmax_kernel<<<dim3(NB / 64), blk, 0, stream>>>(
            hout, W_sp, b_sp, gumbel + (size_t)t * NB * 128, words + (size_t)t * NB);
    }

    eff_kernel<<<dim3(NB / 256), blk, 0, stream>>>(words, eff);

    for (int t = 0; t < NT; ++t) {
        const float* hin = (t % 2 == 0) ? hB : hA;
        float* hout = (t % 2 == 0) ? hA : hB;
        gru_kernel<<<gGemm, blk, 0, stream>>>(
            hin, hout, Whh_r, Wih_r, bih_r, bhh_r,
            eff + (size_t)t * NB, (t == 0) ? 1 : 0);
    }

    // final receiver state: t=9 (odd) wrote hB
    score_kernel<<<dim3(NB / 256), blk, 0, stream>>>(hB, x, W_c, b_c, out);
}

// Round 2
// 5873.774 us; speedup vs baseline: 1.1510x; 1.1510x over previous
//
#include <hip/hip_runtime.h>
#include <math.h>

#define NB 16384
#define NT 10
#define CHM 8192

typedef _Float16 f16;
typedef f16 f16x8 __attribute__((ext_vector_type(8)));
typedef float f32x4 __attribute__((ext_vector_type(4)));

__device__ __forceinline__ float sigm(float v) { return 1.0f / (1.0f + expf(-v)); }

// ---------------- h0 = tanh(feats @ W_in^T + b_in) ----------------
__global__ __launch_bounds__(256) void h0_kernel(
    const float* __restrict__ x, const float* __restrict__ W,
    const float* __restrict__ bias, float* __restrict__ h0)
{
    __shared__ __align__(16) float As[32][128];
    __shared__ __align__(16) float Ws[32][64];
    const int t = threadIdx.x;
    const int tx = t & 15, ty = t >> 4;
    const int mBase = blockIdx.x * 128, nBase = blockIdx.y * 64;
    const int kq = (t & 7) * 4, r8 = t >> 3;

    float4 acc[8];
    #pragma unroll
    for (int mi = 0; mi < 8; ++mi) acc[mi] = make_float4(0.f, 0.f, 0.f, 0.f);

    const float* aPtr = x + (size_t)(mBase + r8) * 272 + 16 + kq;
    const float* wPtr = W + (size_t)(nBase + r8) * 256 + kq;

    for (int kb = 0; kb < 8; ++kb) {
        const int k0 = kb * 32;
        __syncthreads();
        #pragma unroll
        for (int i = 0; i < 4; ++i) {
            float4 v = *(const float4*)(aPtr + (size_t)(i * 32) * 272 + k0);
            const int row = r8 + i * 32;
            const float vv[4] = {v.x, v.y, v.z, v.w};
            #pragma unroll
            for (int j = 0; j < 4; ++j) As[kq + j][row ^ ((kq + j) & 28)] = vv[j];
        }
        #pragma unroll
        for (int i = 0; i < 2; ++i) {
            float4 v = *(const float4*)(wPtr + (size_t)(i * 32) * 256 + k0);
            const int row = r8 + i * 32;
            const float vv[4] = {v.x, v.y, v.z, v.w};
            #pragma unroll
            for (int j = 0; j < 4; ++j) Ws[kq + j][row ^ ((kq + j) & 28)] = vv[j];
        }
        __syncthreads();
        #pragma unroll 8
        for (int k = 0; k < 32; ++k) {
            const int s = k & 28;
            float4 a0 = *(const float4*)&As[k][(ty * 8) ^ s];
            float4 a1 = *(const float4*)&As[k][((ty * 8) + 4) ^ s];
            float4 bb = *(const float4*)&Ws[k][(tx * 4) ^ s];
            const float am[8] = {a0.x, a0.y, a0.z, a0.w, a1.x, a1.y, a1.z, a1.w};
            #pragma unroll
            for (int mi = 0; mi < 8; ++mi) {
                acc[mi].x += am[mi] * bb.x; acc[mi].y += am[mi] * bb.y;
                acc[mi].z += am[mi] * bb.z; acc[mi].w += am[mi] * bb.w;
            }
        }
    }
    const int j0 = nBase + tx * 4;
    const float4 b4 = *(const float4*)&bias[j0];
    #pragma unroll
    for (int mi = 0; mi < 8; ++mi) {
        const int row = mBase + ty * 8 + mi;
        float4 o;
        o.x = tanhf(acc[mi].x + b4.x); o.y = tanhf(acc[mi].y + b4.y);
        o.z = tanhf(acc[mi].z + b4.z); o.w = tanhf(acc[mi].w + b4.w);
        *(float4*)&h0[(size_t)row * 512 + j0] = o;
    }
}

// ---------------- fused sender GRU step (fp32 vector) ----------------
__global__ __launch_bounds__(256) void gru_kernel(
    const float* __restrict__ h_in, float* __restrict__ h_out,
    const float* __restrict__ Whh, const float* __restrict__ Wih,
    const float* __restrict__ bih, const float* __restrict__ bhh,
    const int* __restrict__ words, const int h_zero)
{
    __shared__ __align__(16) float As[32][128];
    __shared__ __align__(16) float Ws[3][32][64];
    const int t = threadIdx.x;
    const int tx = t & 15, ty = t >> 4;
    const int mBase = blockIdx.x * 128, nBase = blockIdx.y * 64;
    const int kq = (t & 7) * 4, r8 = t >> 3;

    float4 acc[3][8];
    #pragma unroll
    for (int g = 0; g < 3; ++g)
        #pragma unroll
        for (int mi = 0; mi < 8; ++mi) acc[g][mi] = make_float4(0.f, 0.f, 0.f, 0.f);

    if (!h_zero) {
        const float* aPtr = h_in + (size_t)(mBase + r8) * 512 + kq;
        const float* w0 = Whh + (size_t)(nBase + r8) * 512 + kq;
        const float* w1 = Whh + (size_t)(512 + nBase + r8) * 512 + kq;
        const float* w2 = Whh + (size_t)(1024 + nBase + r8) * 512 + kq;

        for (int kb = 0; kb < 16; ++kb) {
            const int k0 = kb * 32;
            __syncthreads();
            #pragma unroll
            for (int i = 0; i < 4; ++i) {
                float4 v = *(const float4*)(aPtr + (size_t)(i * 32) * 512 + k0);
                const int row = r8 + i * 32;
                const float vv[4] = {v.x, v.y, v.z, v.w};
                #pragma unroll
                for (int j = 0; j < 4; ++j) As[kq + j][row ^ ((kq + j) & 28)] = vv[j];
            }
            #pragma unroll
            for (int i = 0; i < 2; ++i) {
                const int row = r8 + i * 32;
                float4 v0 = *(const float4*)(w0 + (size_t)(i * 32) * 512 + k0);
                float4 v1 = *(const float4*)(w1 + (size_t)(i * 32) * 512 + k0);
                float4 v2 = *(const float4*)(w2 + (size_t)(i * 32) * 512 + k0);
                const float a0[4] = {v0.x, v0.y, v0.z, v0.w};
                const float a1[4] = {v1.x, v1.y, v1.z, v1.w};
                const float a2[4] = {v2.x, v2.y, v2.z, v2.w};
                #pragma unroll
                for (int j = 0; j < 4; ++j) {
                    const int cc = row ^ ((kq + j) & 28);
                    Ws[0][kq + j][cc] = a0[j]; Ws[1][kq + j][cc] = a1[j]; Ws[2][kq + j][cc] = a2[j];
                }
            }
            __syncthreads();
            #pragma unroll 4
            for (int k = 0; k < 32; ++k) {
                const int s = k & 28;
                float4 a0 = *(const float4*)&As[k][(ty * 8) ^ s];
                float4 a1 = *(const float4*)&As[k][((ty * 8) + 4) ^ s];
                float4 b0 = *(const float4*)&Ws[0][k][(tx * 4) ^ s];
                float4 b1 = *(const float4*)&Ws[1][k][(tx * 4) ^ s];
                float4 b2 = *(const float4*)&Ws[2][k][(tx * 4) ^ s];
                const float am[8] = {a0.x, a0.y, a0.z, a0.w, a1.x, a1.y, a1.z, a1.w};
                #pragma unroll
                for (int mi = 0; mi < 8; ++mi) {
                    acc[0][mi].x += am[mi] * b0.x; acc[0][mi].y += am[mi] * b0.y;
                    acc[0][mi].z += am[mi] * b0.z; acc[0][mi].w += am[mi] * b0.w;
                    acc[1][mi].x += am[mi] * b1.x; acc[1][mi].y += am[mi] * b1.y;
                    acc[1][mi].z += am[mi] * b1.z; acc[1][mi].w += am[mi] * b1.w;
                    acc[2][mi].x += am[mi] * b2.x; acc[2][mi].y += am[mi] * b2.y;
                    acc[2][mi].z += am[mi] * b2.z; acc[2][mi].w += am[mi] * b2.w;
                }
            }
        }
    }

    const int j0 = nBase + tx * 4;
    const float4 br = *(const float4*)&bih[j0];
    const float4 bz = *(const float4*)&bih[512 + j0];
    const float4 bn = *(const float4*)&bih[1024 + j0];
    const float4 cr = *(const float4*)&bhh[j0];
    const float4 cz = *(const float4*)&bhh[512 + j0];
    const float4 cn = *(const float4*)&bhh[1024 + j0];

    #pragma unroll
    for (int mi = 0; mi < 8; ++mi) {
        const int row = mBase + ty * 8 + mi;
        const int idx = words ? words[row] : -1;
        float wr[4] = {0.f,0.f,0.f,0.f}, wz[4] = {0.f,0.f,0.f,0.f}, wn[4] = {0.f,0.f,0.f,0.f};
        if (idx >= 0) {
            #pragma unroll
            for (int nj = 0; nj < 4; ++nj) {
                wr[nj] = Wih[(size_t)(j0 + nj) * 128 + idx];
                wz[nj] = Wih[(size_t)(512 + j0 + nj) * 128 + idx];
                wn[nj] = Wih[(size_t)(1024 + j0 + nj) * 128 + idx];
            }
        }
        float4 hold = make_float4(0.f, 0.f, 0.f, 0.f);
        if (!h_zero) hold = *(const float4*)&h_in[(size_t)row * 512 + j0];
        float4 o;
        { float r = sigm((wr[0]+br.x)+(acc[0][mi].x+cr.x)); float z = sigm((wz[0]+bz.x)+(acc[1][mi].x+cz.x));
          float n = tanhf((wn[0]+bn.x)+r*(acc[2][mi].x+cn.x)); o.x = (1.f-z)*n + z*hold.x; }
        { float r = sigm((wr[1]+br.y)+(acc[0][mi].y+cr.y)); float z = sigm((wz[1]+bz.y)+(acc[1][mi].y+cz.y));
          float n = tanhf((wn[1]+bn.y)+r*(acc[2][mi].y+cn.y)); o.y = (1.f-z)*n + z*hold.y; }
        { float r = sigm((wr[2]+br.z)+(acc[0][mi].z+cr.z)); float z = sigm((wz[2]+bz.z)+(acc[1][mi].z+cz.z));
          float n = tanhf((wn[2]+bn.z)+r*(acc[2][mi].z+cn.z)); o.z = (1.f-z)*n + z*hold.z; }
        { float r = sigm((wr[3]+br.w)+(acc[0][mi].w+cr.w)); float z = sigm((wz[3]+bz.w)+(acc[1][mi].w+cz.w));
          float n = tanhf((wn[3]+bn.w)+r*(acc[2][mi].w+cn.w)); o.w = (1.f-z)*n + z*hold.w; }
        *(float4*)&h_out[(size_t)row * 512 + j0] = o;
    }
}

// ---------------- logits + gumbel argmax ----------------
__global__ __launch_bounds__(256) void argmax_kernel(
    const float* __restrict__ h, const float* __restrict__ Wsp,
    const float* __restrict__ bsp, const float* __restrict__ gum,
    int* __restrict__ wout)
{
    __shared__ __align__(16) float As[32][64];
    __shared__ __align__(16) float Ws[32][128];
    const int t = threadIdx.x;
    const int tx = t & 31, ty = t >> 5;
    const int mBase = blockIdx.x * 64;
    const int kq = (t & 7) * 4, r8 = t >> 3;

    float4 acc[8];
    #pragma unroll
    for (int mi = 0; mi < 8; ++mi) acc[mi] = make_float4(0.f, 0.f, 0.f, 0.f);

    const float* aPtr = h + (size_t)(mBase + r8) * 512 + kq;
    const float* wPtr = Wsp + (size_t)r8 * 512 + kq;

    for (int kb = 0; kb < 16; ++kb) {
        const int k0 = kb * 32;
        __syncthreads();
        #pragma unroll
        for (int i = 0; i < 2; ++i) {
            float4 v = *(const float4*)(aPtr + (size_t)(i * 32) * 512 + k0);
            const int row = r8 + i * 32;
            const float vv[4] = {v.x, v.y, v.z, v.w};
            #pragma unroll
            for (int j = 0; j < 4; ++j) As[kq + j][row ^ ((kq + j) & 28)] = vv[j];
        }
        #pragma unroll
        for (int i = 0; i < 4; ++i) {
            float4 v = *(const float4*)(wPtr + (size_t)(i * 32) * 512 + k0);
            const int row = r8 + i * 32;
            const float vv[4] = {v.x, v.y, v.z, v.w};
            #pragma unroll
            for (int j = 0; j < 4; ++j) Ws[kq + j][row ^ ((kq + j) & 28)] = vv[j];
        }
        __syncthreads();
        #pragma unroll 8
        for (int k = 0; k < 32; ++k) {
            const int s = k & 28;
            float4 a0 = *(const float4*)&As[k][(ty * 8) ^ s];
            float4 a1 = *(const float4*)&As[k][((ty * 8) + 4) ^ s];
            float4 bb = *(const float4*)&Ws[k][(tx * 4) ^ s];
            const float am[8] = {a0.x, a0.y, a0.z, a0.w, a1.x, a1.y, a1.z, a1.w};
            #pragma unroll
            for (int mi = 0; mi < 8; ++mi) {
                acc[mi].x += am[mi] * bb.x; acc[mi].y += am[mi] * bb.y;
                acc[mi].z += am[mi] * bb.z; acc[mi].w += am[mi] * bb.w;
            }
        }
    }

    const float4 b4 = *(const float4*)&bsp[tx * 4];
    #pragma unroll
    for (int mi = 0; mi < 8; ++mi) {
        const int row = mBase + ty * 8 + mi;
        const float4 g4 = *(const float4*)&gum[(size_t)row * 128 + tx * 4];
        float v[4];
        v[0] = acc[mi].x + b4.x + g4.x; v[1] = acc[mi].y + b4.y + g4.y;
        v[2] = acc[mi].z + b4.z + g4.z; v[3] = acc[mi].w + b4.w + g4.w;
        float bv = v[0]; int bi = tx * 4;
        #pragma unroll
        for (int nj = 1; nj < 4; ++nj) if (v[nj] > bv) { bv = v[nj]; bi = tx * 4 + nj; }
        #pragma unroll
        for (int off = 1; off <= 16; off <<= 1) {
            float ov = __shfl_xor(bv, off, 64);
            int oi = __shfl_xor(bi, off, 64);
            if (ov > bv || (ov == bv && oi < bi)) { bv = ov; bi = oi; }
        }
        if (tx == 0) wout[row] = bi;
    }
}

// ---------------- alive mask -> effective word (-1 = zero input) ----------------
__global__ __launch_bounds__(256) void eff_kernel(
    const int* __restrict__ words, int* __restrict__ eff)
{
    const int b = blockIdx.x * 256 + threadIdx.x;
    int alive = 1;
    #pragma unroll
    for (int t = 0; t < NT; ++t) {
        const int w = words[(size_t)t * NB + b];
        eff[(size_t)t * NB + b] = alive ? w : -1;
        alive = alive & (w != 0);
    }
}

// ---------------- weight split: Whh_r -> hi/lo fp16 in [kg][1536][8] ----------------
__global__ __launch_bounds__(256) void wsplit_kernel(
    const float* __restrict__ W, f16* __restrict__ whi, f16* __restrict__ wlo)
{
    const int u = blockIdx.x * 256 + threadIdx.x;   // 98304 = 64*1536
    const int kg = u / 1536, row = u - kg * 1536;
    const float* s = W + (size_t)row * 512 + kg * 8;
    f16x8 hi8, lo8;
    #pragma unroll
    for (int i = 0; i < 8; ++i) {
        float v = s[i];
        f16 hv = (f16)v;
        hi8[i] = hv;
        lo8[i] = (f16)(v - (float)hv);
    }
    *(f16x8*)&whi[(size_t)u * 8] = hi8;
    *(f16x8*)&wlo[(size_t)u * 8] = lo8;
}

// ---------------- Wih_r transpose -> [128][1536] fp32 ----------------
__global__ __launch_bounds__(256) void wihT_kernel(
    const float* __restrict__ Wih, float* __restrict__ WihT)
{
    const int u = blockIdx.x * 256 + threadIdx.x;   // 196608 = 128*1536
    const int w = u / 1536, c = u - w * 1536;
    WihT[u] = Wih[(size_t)c * 128 + w];
}

// ---------------- receiver GEMM: gh = h @ Whh_r^T via fp16 hi/lo split MFMA ----------------
// grid (CHM/128, 1536/128), block 256 (4 waves, 2x2 wave grid, wave tile 64x64)
__global__ __launch_bounds__(256) void gemm_recv(
    const f16* __restrict__ h_hi, const f16* __restrict__ h_lo,
    const f16* __restrict__ w_hi, const f16* __restrict__ w_lo,
    f16* __restrict__ gh, int rowBase)
{
    __shared__ __align__(16) f16 lds[2048 * 8];   // Ah | Al | Bh | Bl, each 512 units of 16B
    const int t = threadIdx.x;
    const int lane = t & 63;
    const int wave = t >> 6;
    const int wm = wave >> 1, wn = wave & 1;
    const int m0 = rowBase + blockIdx.x * 128;
    const int n0 = blockIdx.y * 128;

    const f32x4 z4 = {0.f, 0.f, 0.f, 0.f};
    f32x4 acc[4][4];
    #pragma unroll
    for (int mi = 0; mi < 4; ++mi)
        #pragma unroll
        for (int ni = 0; ni < 4; ++ni) acc[mi][ni] = z4;

    const int abase = (((lane >> 4) << 7) + wm * 64 + (lane & 15)) * 8;
    const int bbase = (((lane >> 4) << 7) + wn * 64 + (lane & 15)) * 8;

    for (int kb = 0; kb < 16; ++kb) {
        const int kg0 = kb * 4;
        // ---- stage 32KB via regs ----
        f16x8 st[8];
        #pragma unroll
        for (int i = 0; i < 8; ++i) {
            const int u = i * 256 + t;
            const int kg = kg0 + ((u >> 7) & 3);
            const int row = u & 127;
            const f16* src;
            if ((i >> 1) == 0)      src = h_hi + ((size_t)kg * NB + m0 + row) * 8;
            else if ((i >> 1) == 1) src = h_lo + ((size_t)kg * NB + m0 + row) * 8;
            else if ((i >> 1) == 2) src = w_hi + ((size_t)kg * 1536 + n0 + row) * 8;
            else                    src = w_lo + ((size_t)kg * 1536 + n0 + row) * 8;
            st[i] = *(const f16x8*)src;
        }
        __syncthreads();
        #pragma unroll
        for (int i = 0; i < 8; ++i) *(f16x8*)&lds[(size_t)(i * 256 + t) * 8] = st[i];
        __syncthreads();

        // ---- fragments + MFMA ----
        f16x8 ah[4], al[4], bh[4], bl[4];
        #pragma unroll
        for (int mi = 0; mi < 4; ++mi) {
            ah[mi] = *(const f16x8*)&lds[abase + mi * 128];
            al[mi] = *(const f16x8*)&lds[4096 + abase + mi * 128];
        }
        #pragma unroll
        for (int ni = 0; ni < 4; ++ni) {
            bh[ni] = *(const f16x8*)&lds[8192 + bbase + ni * 128];
            bl[ni] = *(const f16x8*)&lds[12288 + bbase + ni * 128];
        }
        #pragma unroll
        for (int mi = 0; mi < 4; ++mi)
            #pragma unroll
            for (int ni = 0; ni < 4; ++ni) {
                acc[mi][ni] = __builtin_amdgcn_mfma_f32_16x16x32_f16(ah[mi], bh[ni], acc[mi][ni], 0, 0, 0);
                acc[mi][ni] = __builtin_amdgcn_mfma_f32_16x16x32_f16(ah[mi], bl[ni], acc[mi][ni], 0, 0, 0);
                acc[mi][ni] = __builtin_amdgcn_mfma_f32_16x16x32_f16(al[mi], bh[ni], acc[mi][ni], 0, 0, 0);
            }
    }

    // ---- epilogue: gh in [cg=col/8][CHM][8] fp16 layout ----
    const int colb = n0 + wn * 64 + (lane & 15);
    const int rowb = blockIdx.x * 128 + wm * 64 + ((lane >> 4) << 2);
    #pragma unroll
    for (int mi = 0; mi < 4; ++mi)
        #pragma unroll
        for (int ni = 0; ni < 4; ++ni) {
            const int col = colb + ni * 16;
            #pragma unroll
            for (int j = 0; j < 4; ++j) {
                const int rl = rowb + mi * 16 + j;
                gh[((size_t)(col >> 3) * CHM + rl) * 8 + (col & 7)] = (f16)acc[mi][ni][j];
            }
        }
}

// ---------------- receiver GRU update (elementwise) ----------------
// grid CHM/64, block 256: wave = 64 consecutive rows, q = t>>6 selects kg phase
__global__ __launch_bounds__(256) void recv_update(
    f16* __restrict__ h_hi, f16* __restrict__ h_lo,
    const f16* __restrict__ gh,
    const float* __restrict__ WihT,
    const float* __restrict__ bih, const float* __restrict__ bhh,
    const int* __restrict__ effw,
    int rowBase, int flags)   // flags bit0: gh==0, bit1: h==0
{
    const int t = threadIdx.x;
    const int r = t & 63, q = t >> 6;
    const int rowL = blockIdx.x * 64 + r;
    const int row = rowBase + rowL;
    const int word = effw[row];

    for (int kk = 0; kk < 16; ++kk) {
        const int kg = q + kk * 4;
        const int c0 = kg * 8;
        float gr[8], gz[8], gn[8], hp[8];
        if (!(flags & 1)) {
            f16x8 vr = *(const f16x8*)&gh[((size_t)kg * CHM + rowL) * 8];
            f16x8 vz = *(const f16x8*)&gh[((size_t)(kg + 64) * CHM + rowL) * 8];
            f16x8 vn = *(const f16x8*)&gh[((size_t)(kg + 128) * CHM + rowL) * 8];
            #pragma unroll
            for (int i = 0; i < 8; ++i) { gr[i] = (float)vr[i]; gz[i] = (float)vz[i]; gn[i] = (float)vn[i]; }
        } else {
            #pragma unroll
            for (int i = 0; i < 8; ++i) { gr[i] = 0.f; gz[i] = 0.f; gn[i] = 0.f; }
        }
        if (!(flags & 2)) {
            f16x8 vh = *(const f16x8*)&h_hi[((size_t)kg * NB + row) * 8];
            f16x8 vl = *(const f16x8*)&h_lo[((size_t)kg * NB + row) * 8];
            #pragma unroll
            for (int i = 0; i < 8; ++i) hp[i] = (float)vh[i] + (float)vl[i];
        } else {
            #pragma unroll
            for (int i = 0; i < 8; ++i) hp[i] = 0.f;
        }
        float wir[8], wiz[8], win[8];
        if (word >= 0) {
            const float* wt = WihT + (size_t)word * 1536;
            #pragma unroll
            for (int i = 0; i < 8; ++i) {
                wir[i] = wt[c0 + i];
                wiz[i] = wt[512 + c0 + i];
                win[i] = wt[1024 + c0 + i];
            }
        } else {
            #pragma unroll
            for (int i = 0; i < 8; ++i) { wir[i] = 0.f; wiz[i] = 0.f; win[i] = 0.f; }
        }
        f16x8 oh, ol;
        #pragma unroll
        for (int i = 0; i < 8; ++i) {
            float rr = sigm(wir[i] + bih[c0 + i] + gr[i] + bhh[c0 + i]);
            float zz = sigm(wiz[i] + bih[512 + c0 + i] + gz[i] + bhh[512 + c0 + i]);
            float nn = tanhf(win[i] + bih[1024 + c0 + i] + rr * (gn[i] + bhh[1024 + c0 + i]));
            float hv = (1.f - zz) * nn + zz * hp[i];
            f16 hh = (f16)hv;
            oh[i] = hh;
            ol[i] = (f16)(hv - (float)hh);
        }
        *(f16x8*)&h_hi[((size_t)kg * NB + row) * 8] = oh;
        *(f16x8*)&h_lo[((size_t)kg * NB + row) * 8] = ol;
    }
}

// ---------------- score = [h_n, task] @ W_c^T + b_c ----------------
__global__ __launch_bounds__(256) void score_kernel(
    const f16* __restrict__ h_hi, const f16* __restrict__ h_lo,
    const float* __restrict__ x, const float* __restrict__ Wc,
    const float* __restrict__ bc, float* __restrict__ out)
{
    __shared__ float Wcs[10][528];
    const int t = threadIdx.x;
    for (int q = t; q < 1320; q += 256)
        *(float4*)&(((float*)Wcs)[q * 4]) = *(const float4*)&Wc[q * 4];
    __syncthreads();

    const int row = blockIdx.x * 256 + t;
    float acc[10];
    #pragma unroll
    for (int d = 0; d < 10; ++d) acc[d] = 0.f;

    for (int kg = 0; kg < 64; ++kg) {
        f16x8 vh = *(const f16x8*)&h_hi[((size_t)kg * NB + row) * 8];
        f16x8 vl = *(const f16x8*)&h_lo[((size_t)kg * NB + row) * 8];
        #pragma unroll
        for (int i = 0; i < 8; ++i) {
            const float v = (float)vh[i] + (float)vl[i];
            #pragma unroll
            for (int d = 0; d < 10; ++d) acc[d] += v * Wcs[d][kg * 8 + i];
        }
    }
    #pragma unroll
    for (int j = 0; j < 16; ++j) {
        const float tv = x[(size_t)row * 272 + j];
        #pragma unroll
        for (int d = 0; d < 10; ++d) acc[d] += tv * Wcs[d][512 + j];
    }
    #pragma unroll
    for (int d = 0; d < 10; ++d) out[(size_t)row * 10 + d] = acc[d] + bc[d];
}

extern "C" void kernel_launch(void* const* d_in, const int* in_sizes, int n_in,
                              void* d_out, int out_size, void* d_ws, size_t ws_size,
                              hipStream_t stream) {
    const float* x      = (const float*)d_in[0];
    const float* gumbel = (const float*)d_in[1];
    const float* W_in   = (const float*)d_in[2];
    const float* b_in   = (const float*)d_in[3];
    const float* Wih_s  = (const float*)d_in[4];
    const float* Whh_s  = (const float*)d_in[5];
    const float* bih_s  = (const float*)d_in[6];
    const float* bhh_s  = (const float*)d_in[7];
    const float* W_sp   = (const float*)d_in[8];
    const float* b_sp   = (const float*)d_in[9];
    const float* Wih_r  = (const float*)d_in[10];
    const float* Whh_r  = (const float*)d_in[11];
    const float* bih_r  = (const float*)d_in[12];
    const float* bhh_r  = (const float*)d_in[13];
    const float* W_c    = (const float*)d_in[14];
    const float* b_c    = (const float*)d_in[15];
    float* out = (float*)d_out;

    float* hA = (float*)d_ws;                       // 32MB (sender ping; receiver h_hi/h_lo)
    float* hB = hA + (size_t)NB * 512;              // 32MB (sender pong; receiver gh + w split + WihT)
    int* words = (int*)(hB + (size_t)NB * 512);
    int* eff = words + (size_t)NT * NB;

    f16* h_hi = (f16*)hA;
    f16* h_lo = h_hi + (size_t)64 * NB * 8;         // +16MB
    f16* gh   = (f16*)hB;                            // 25,165,824 B
    f16* w_hi = (f16*)((char*)hB + 25165824);        // 1,572,864 B
    f16* w_lo = (f16*)((char*)hB + 25165824 + 1572864);
    float* WihT = (float*)((char*)hB + 25165824 + 2 * 1572864); // 786,432 B

    const dim3 blk(256);
    const dim3 gGemm(NB / 128, 512 / 64);

    // ---- sender (fp32, unchanged) ----
    h0_kernel<<<gGemm, blk, 0, stream>>>(x, W_in, b_in, hA);
    for (int t = 0; t < NT; ++t) {
        const float* hin = (t % 2 == 0) ? hA : hB;
        float* hout = (t % 2 == 0) ? hB : hA;
        gru_kernel<<<gGemm, blk, 0, stream>>>(
            hin, hout, Whh_s, Wih_s, bih_s, bhh_s,
            (t == 0) ? (const int*)nullptr : (words + (size_t)(t - 1) * NB), 0);
        argmax_kernel<<<dim3(NB / 64), blk, 0, stream>>>(
            hout, W_sp, b_sp, gumbel + (size_t)t * NB * 128, words + (size_t)t * NB);
    }
    eff_kernel<<<dim3(NB / 256), blk, 0, stream>>>(words, eff);

    // ---- receiver prep (after sender: hA/hB free) ----
    wsplit_kernel<<<dim3(384), blk, 0, stream>>>(Whh_r, w_hi, w_lo);
    wihT_kernel<<<dim3(768), blk, 0, stream>>>(Wih_r, WihT);

    // ---- receiver (fp16 split MFMA) ----
    recv_update<<<dim3(CHM / 64), blk, 0, stream>>>(h_hi, h_lo, gh, WihT, bih_r, bhh_r, eff, 0, 3);
    recv_update<<<dim3(CHM / 64), blk, 0, stream>>>(h_hi, h_lo, gh, WihT, bih_r, bhh_r, eff, CHM, 3);
    for (int t = 1; t < NT; ++t) {
        const int* ef = eff + (size_t)t * NB;
        gemm_recv<<<dim3(CHM / 128, 1536 / 128), blk, 0, stream>>>(h_hi, h_lo, w_hi, w_lo, gh, 0);
        recv_update<<<dim3(CHM / 64), blk, 0, stream>>>(h_hi, h_lo, gh, WihT, bih_r, bhh_r, ef, 0, 0);
        gemm_recv<<<dim3(CHM / 128, 1536 / 128), blk, 0, stream>>>(h_hi, h_lo, w_hi, w_lo, gh, CHM);
        recv_update<<<dim3(CHM / 64), blk, 0, stream>>>(h_hi, h_lo, gh, WihT, bih_r, bhh_r, ef, CHM, 0);
    }

    score_kernel<<<dim3(NB / 256), blk, 0, stream>>>(h_hi, h_lo, x, W_c, b_c, out);
}